// Round 1
// baseline (470.054 us; speedup 1.0000x reference)
//
#include <hip/hip_runtime.h>
#include <cstdint>
#include <cstddef>

// Entropic Sinkhorn loss, MI355X / gfx950.
// Pipeline:
//   1. cast fp32 features -> bf16
//   2. GEMM (MFMA 16x16x32 bf16) S = img@txt^T fused with K = exp((S-1)*100), K stored bf16 (128 MiB)
//   3. 5 Sinkhorn iterations for BOTH problems (K and K^T) simultaneously:
//      each iteration = 2 passes over K, each pass does one row-reduce and one col-reduce
//   4. final pass: row/col sums of exp(u_i K_ij v_j) -> log-softmax -> scalar loss
// Loss is invariant under K -> K^T (the two sub-problems swap), so a transposed
// GEMM C-layout cannot corrupt the result.

#define N_DIM 8192
#define D_DIM 256

typedef __attribute__((ext_vector_type(8))) short short8;
typedef __attribute__((ext_vector_type(4))) float f32x4;

__device__ __forceinline__ float bf2f(unsigned short u) {
  union { unsigned int i; float f; } x; x.i = ((unsigned int)u) << 16; return x.f;
}
__device__ __forceinline__ unsigned short f2bf(float f) {
  union { float ff; unsigned int i; } x; x.ff = f;
  unsigned int r = x.i + 0x7FFFu + ((x.i >> 16) & 1u);  // RNE
  return (unsigned short)(r >> 16);
}

// ---------------- 1. fp32 -> bf16 cast ----------------
__global__ __launch_bounds__(256) void cast_bf16_kernel(const float* __restrict__ src,
                                                        unsigned short* __restrict__ dst,
                                                        int n4) {
  int i = blockIdx.x * blockDim.x + threadIdx.x;
  if (i < n4) {
    float4 f = reinterpret_cast<const float4*>(src)[i];
    ushort4 o;
    o.x = f2bf(f.x); o.y = f2bf(f.y); o.z = f2bf(f.z); o.w = f2bf(f.w);
    reinterpret_cast<ushort4*>(dst)[i] = o;
  }
}

// ---------------- 2. GEMM + exp ----------------
// Block: 256 thr (4 waves, 2x2), tile 128x128, wave tile 64x64 = 4x4 frags of 16x16.
// K-dim = 256 -> 8 steps of 32. Fragments loaded directly from global (features are
// 4 MiB each -> L2/L3 resident). Epilogue repacks through LDS for coalesced stores.
__global__ __launch_bounds__(256) void gemm_exp_kernel(const unsigned short* __restrict__ A,
                                                       const unsigned short* __restrict__ B,
                                                       unsigned short* __restrict__ Kout) {
  const int bi = blockIdx.y, bj = blockIdx.x;
  const int t = threadIdx.x;
  const int lane = t & 63, wid = t >> 6;
  const int wr = wid >> 1, wc = wid & 1;
  const int al = lane & 15, kh = lane >> 4;

  f32x4 acc[4][4] = {};

  const unsigned short* Abase = A + (size_t)(bi * 128 + wr * 64 + al) * D_DIM + kh * 8;
  const unsigned short* Bbase = B + (size_t)(bj * 128 + wc * 64 + al) * D_DIM + kh * 8;

  #pragma unroll
  for (int kk = 0; kk < 8; ++kk) {
    short8 a[4], b[4];
    #pragma unroll
    for (int m = 0; m < 4; ++m)
      a[m] = *reinterpret_cast<const short8*>(Abase + (size_t)m * 16 * D_DIM + kk * 32);
    #pragma unroll
    for (int n = 0; n < 4; ++n)
      b[n] = *reinterpret_cast<const short8*>(Bbase + (size_t)n * 16 * D_DIM + kk * 32);
    #pragma unroll
    for (int m = 0; m < 4; ++m)
      #pragma unroll
      for (int n = 0; n < 4; ++n)
        acc[m][n] = __builtin_amdgcn_mfma_f32_16x16x32_bf16(a[m], b[n], acc[m][n], 0, 0, 0);
  }

  // Epilogue: exp + bf16 + LDS repack (row stride 136 elems = 272B, 16B-aligned, breaks
  // the worst bank conflicts), then coalesced 16B global stores.
  __shared__ unsigned short Cs[128 * 136];
  #pragma unroll
  for (int m = 0; m < 4; ++m)
    #pragma unroll
    for (int n = 0; n < 4; ++n)
      #pragma unroll
      for (int q = 0; q < 4; ++q) {
        float s = acc[m][n][q];
        float kv = __expf((s - 1.0f) * 100.0f);
        int rr = wr * 64 + m * 16 + kh * 4 + q;  // C/D layout: col=lane&15, row=(lane>>4)*4+q
        int cc = wc * 64 + n * 16 + al;
        Cs[rr * 136 + cc] = f2bf(kv);
      }
  __syncthreads();
  const int row = t >> 1, half = (t & 1) * 64;
  size_t gbase = (size_t)(bi * 128 + row) * N_DIM + bj * 128 + half;
  #pragma unroll
  for (int c = 0; c < 8; ++c) {
    *reinterpret_cast<short8*>(Kout + gbase + c * 8) =
        *reinterpret_cast<const short8*>(&Cs[row * 136 + half + c * 8]);
  }
}

// ---------------- 3. init ----------------
__global__ __launch_bounds__(256) void init_vecs_kernel(float* __restrict__ u,
                                                        float* __restrict__ u2,
                                                        float* __restrict__ out) {
  int i = blockIdx.x * blockDim.x + threadIdx.x;
  if (i < N_DIM) { u[i] = 1.0f / N_DIM; u2[i] = 1.0f / N_DIM; }
  if (i == 0) out[0] = 0.0f;
}

// ---------------- 4. dual matvec: rowsum_i = sum_j K_ij*wcol_j ; colpart = partial sum_i K_ij*wrow_i
// Block: 1024 thr covers a FULL 32-row x 8192-col stripe -> rowsum written directly,
// col partials (one 8192-vector per stripe) reduced by a follow-up kernel.
__global__ __launch_bounds__(1024) void dual_matvec_kernel(const unsigned short* __restrict__ Km,
                                                           const float* __restrict__ wrow,
                                                           const float* __restrict__ wcol,
                                                           float* __restrict__ rowsum,
                                                           float* __restrict__ colpart) {
  const int b = blockIdx.x;          // 256 stripes
  const int t = threadIdx.x;         // 1024
  const int lane = t & 63, wid = t >> 6;
  const int c0 = t * 8;
  const int row0 = b * 32;

  float wc8[8];
  {
    float4 w0 = *reinterpret_cast<const float4*>(wcol + c0);
    float4 w1 = *reinterpret_cast<const float4*>(wcol + c0 + 4);
    wc8[0] = w0.x; wc8[1] = w0.y; wc8[2] = w0.z; wc8[3] = w0.w;
    wc8[4] = w1.x; wc8[5] = w1.y; wc8[6] = w1.z; wc8[7] = w1.w;
  }
  float colacc[8] = {0, 0, 0, 0, 0, 0, 0, 0};
  __shared__ float wred[32][16];

  for (int r = 0; r < 32; ++r) {
    float wr = wrow[row0 + r];  // uniform -> scalar load
    short8 kv = *reinterpret_cast<const short8*>(Km + (size_t)(row0 + r) * N_DIM + c0);
    float p = 0.0f;
    #pragma unroll
    for (int e = 0; e < 8; ++e) {
      float kf = bf2f((unsigned short)kv[e]);
      p += kf * wc8[e];
      colacc[e] += kf * wr;
    }
    #pragma unroll
    for (int off = 32; off > 0; off >>= 1) p += __shfl_down(p, off, 64);
    if (lane == 0) wred[r][wid] = p;
  }
  __syncthreads();
  if (t < 32) {
    float s = 0.0f;
    #pragma unroll
    for (int w = 0; w < 16; ++w) s += wred[t][w];
    rowsum[row0 + t] = s;
  }
  *reinterpret_cast<float4*>(colpart + (size_t)b * N_DIM + c0) =
      make_float4(colacc[0], colacc[1], colacc[2], colacc[3]);
  *reinterpret_cast<float4*>(colpart + (size_t)b * N_DIM + c0 + 4) =
      make_float4(colacc[4], colacc[5], colacc[6], colacc[7]);
}

// ---------------- 5. reduce col partials + elementwise transform ----------------
// colvec_out[j] = coeff / sum_stripes colpart[s][j] ; rowvec_out[i] = coeff / rowsum[i]
__global__ __launch_bounds__(256) void reduce_transform_kernel(const float* __restrict__ colpart,
                                                               const float* __restrict__ rowsum,
                                                               float* __restrict__ colvec_out,
                                                               float* __restrict__ rowvec_out,
                                                               float coeff) {
  int b = blockIdx.x;               // 256 blocks, 32 cols each
  int jloc = threadIdx.x & 31;
  int chunk = threadIdx.x >> 5;     // 8 chunks of 32 stripes
  int j = b * 32 + jloc;
  float s = 0.0f;
  for (int st = chunk * 32; st < chunk * 32 + 32; ++st)
    s += colpart[(size_t)st * N_DIM + j];
  __shared__ float red[8][32];
  red[chunk][jloc] = s;
  __syncthreads();
  if (threadIdx.x < 32) {
    int jj = b * 32 + threadIdx.x;
    float tot = 0.0f;
    #pragma unroll
    for (int c = 0; c < 8; ++c) tot += red[c][threadIdx.x];
    colvec_out[jj] = coeff / tot;
    rowvec_out[jj] = coeff / rowsum[jj];
  }
}

// ---------------- 6. final pass: softmax denominators of P and P' ----------------
// rowsumE_i = sum_j exp(u_i K_ij v_j) ; colpartE partials of sum_i exp(u2_j K_ij v2_i)
__global__ __launch_bounds__(1024) void final_dual_kernel(const unsigned short* __restrict__ Km,
                                                          const float* __restrict__ u,
                                                          const float* __restrict__ v,
                                                          const float* __restrict__ u2,
                                                          const float* __restrict__ v2,
                                                          float* __restrict__ rowsumE,
                                                          float* __restrict__ colpartE) {
  const int b = blockIdx.x;
  const int t = threadIdx.x;
  const int lane = t & 63, wid = t >> 6;
  const int c0 = t * 8;
  const int row0 = b * 32;

  float v8[8], u28[8];
  {
    float4 a0 = *reinterpret_cast<const float4*>(v + c0);
    float4 a1 = *reinterpret_cast<const float4*>(v + c0 + 4);
    v8[0] = a0.x; v8[1] = a0.y; v8[2] = a0.z; v8[3] = a0.w;
    v8[4] = a1.x; v8[5] = a1.y; v8[6] = a1.z; v8[7] = a1.w;
    float4 b0 = *reinterpret_cast<const float4*>(u2 + c0);
    float4 b1 = *reinterpret_cast<const float4*>(u2 + c0 + 4);
    u28[0] = b0.x; u28[1] = b0.y; u28[2] = b0.z; u28[3] = b0.w;
    u28[4] = b1.x; u28[5] = b1.y; u28[6] = b1.z; u28[7] = b1.w;
  }
  float colacc[8] = {0, 0, 0, 0, 0, 0, 0, 0};
  __shared__ float wred[32][16];

  for (int r = 0; r < 32; ++r) {
    float ui = u[row0 + r];
    float v2i = v2[row0 + r];
    short8 kv = *reinterpret_cast<const short8*>(Km + (size_t)(row0 + r) * N_DIM + c0);
    float p = 0.0f;
    #pragma unroll
    for (int e = 0; e < 8; ++e) {
      float kf = bf2f((unsigned short)kv[e]);
      p += __expf(ui * kf * v8[e]);          // P_ij, then exp for softmax denom
      colacc[e] += __expf(u28[e] * kf * v2i); // P'_ji term
    }
    #pragma unroll
    for (int off = 32; off > 0; off >>= 1) p += __shfl_down(p, off, 64);
    if (lane == 0) wred[r][wid] = p;
  }
  __syncthreads();
  if (t < 32) {
    float s = 0.0f;
    #pragma unroll
    for (int w = 0; w < 16; ++w) s += wred[t][w];
    rowsumE[row0 + t] = s;
  }
  *reinterpret_cast<float4*>(colpartE + (size_t)b * N_DIM + c0) =
      make_float4(colacc[0], colacc[1], colacc[2], colacc[3]);
  *reinterpret_cast<float4*>(colpartE + (size_t)b * N_DIM + c0 + 4) =
      make_float4(colacc[4], colacc[5], colacc[6], colacc[7]);
}

// ---------------- 7. final reduction -> scalar loss ----------------
__global__ __launch_bounds__(256) void final_reduce_kernel(const float* __restrict__ colpartE,
                                                           const float* __restrict__ rowsumE,
                                                           const unsigned short* __restrict__ Km,
                                                           const float* __restrict__ u,
                                                           const float* __restrict__ v,
                                                           const float* __restrict__ u2,
                                                           const float* __restrict__ v2,
                                                           float* __restrict__ out) {
  int b = blockIdx.x;               // 256 blocks, 32 rows each
  int jloc = threadIdx.x & 31;
  int chunk = threadIdx.x >> 5;
  int j = b * 32 + jloc;
  float s = 0.0f;
  for (int st = chunk * 32; st < chunk * 32 + 32; ++st)
    s += colpartE[(size_t)st * N_DIM + j];
  __shared__ float red[8][32];
  red[chunk][jloc] = s;
  __syncthreads();
  if (threadIdx.x < 32) {
    int i = b * 32 + threadIdx.x;
    float s2 = 0.0f;
    #pragma unroll
    for (int c = 0; c < 8; ++c) s2 += red[c][threadIdx.x];
    float kd = bf2f(Km[(size_t)i * N_DIM + i]);
    float l1 = logf(rowsumE[i]) - u[i] * kd * v[i];    // lse_i - P_ii
    float l2 = logf(s2) - u2[i] * kd * v2[i];          // problem 2
    float val = l1 + l2;
    #pragma unroll
    for (int o = 16; o > 0; o >>= 1) val += __shfl_down(val, o, 64);
    if (threadIdx.x == 0) atomicAdd(out, val * (0.5f / (float)N_DIM));
  }
}

// ---------------- launch ----------------
extern "C" void kernel_launch(void* const* d_in, const int* in_sizes, int n_in,
                              void* d_out, int out_size, void* d_ws, size_t ws_size,
                              hipStream_t stream) {
  const float* img = (const float*)d_in[0];
  const float* txt = (const float*)d_in[1];
  float* out = (float*)d_out;

  char* ws = (char*)d_ws;
  size_t off = 0;
  auto alloc = [&](size_t bytes) -> void* {
    void* p = ws + off;
    off += (bytes + 255) & ~(size_t)255;
    return p;
  };
  unsigned short* Km  = (unsigned short*)alloc((size_t)N_DIM * N_DIM * 2);  // 128 MiB
  unsigned short* Abf = (unsigned short*)alloc((size_t)N_DIM * D_DIM * 2);
  unsigned short* Bbf = (unsigned short*)alloc((size_t)N_DIM * D_DIM * 2);
  float* u       = (float*)alloc(N_DIM * 4);
  float* u2      = (float*)alloc(N_DIM * 4);
  float* v       = (float*)alloc(N_DIM * 4);
  float* v2      = (float*)alloc(N_DIM * 4);
  float* rowsum  = (float*)alloc(N_DIM * 4);
  float* colpart = (float*)alloc((size_t)256 * N_DIM * 4);  // 8 MiB

  if (off > ws_size) {  // signal insufficient workspace distinctly (NaN)
    hipMemsetAsync(d_out, 0xFF, sizeof(float) * (out_size > 0 ? out_size : 1), stream);
    return;
  }

  const int n4 = N_DIM * D_DIM / 4;
  cast_bf16_kernel<<<(n4 + 255) / 256, 256, 0, stream>>>(img, Abf, n4);
  cast_bf16_kernel<<<(n4 + 255) / 256, 256, 0, stream>>>(txt, Bbf, n4);
  gemm_exp_kernel<<<dim3(64, 64), 256, 0, stream>>>(Abf, Bbf, Km);
  init_vecs_kernel<<<32, 256, 0, stream>>>(u, u2, out);

  const float bval = 1.0f / (float)N_DIM;
  for (int it = 0; it < 5; ++it) {
    // pass A: colsum = K^T u -> v = b/colsum ; rowsum = K u2 -> v2 = b/rowsum
    dual_matvec_kernel<<<256, 1024, 0, stream>>>(Km, u, u2, rowsum, colpart);
    reduce_transform_kernel<<<256, 256, 0, stream>>>(colpart, rowsum, v, v2, bval);
    // pass B: colsum = K^T v2 -> u2 = 1/colsum ; rowsum = K v -> u = 1/rowsum
    dual_matvec_kernel<<<256, 1024, 0, stream>>>(Km, v2, v, rowsum, colpart);
    reduce_transform_kernel<<<256, 256, 0, stream>>>(colpart, rowsum, u2, u, 1.0f);
  }

  final_dual_kernel<<<256, 1024, 0, stream>>>(Km, u, v, u2, v2, rowsum, colpart);
  final_reduce_kernel<<<256, 256, 0, stream>>>(colpart, rowsum, Km, u, v, u2, v2, out);
}

// Round 2
// 310.822 us; speedup vs baseline: 1.5123x; 1.5123x over previous
//
#include <hip/hip_runtime.h>
#include <hip/hip_fp16.h>
#include <cstdint>
#include <cstddef>

// Entropic Sinkhorn loss, MI355X / gfx950.  Round 2.
// K stored as fp8 e5m2 (64 MiB) with per-COLUMN power-of-2 scaling (exactly
// absorbed by Sinkhorn for problem 1; negligible trajectory perturbation for
// problem 2 given e^-40 diagonal dominance). GEMM: m97-style LDS-staged MFMA
// with global_load_lds + XOR swizzle, fused exp2/scale/fp8 epilogue.

#define N_DIM 8192
#define D_DIM 256
#define L2E100 144.26950408889634f  // 100 * log2(e)

typedef __attribute__((ext_vector_type(8))) short short8;
typedef __attribute__((ext_vector_type(4))) float f32x4;
typedef __attribute__((ext_vector_type(2))) float f32x2;

__device__ __forceinline__ float bf2f(unsigned short u) {
  union { unsigned int i; float f; } x; x.i = ((unsigned int)u) << 16; return x.f;
}
__device__ __forceinline__ unsigned short f2bf(float f) {
  union { float ff; unsigned int i; } x; x.ff = f;
  unsigned int r = x.i + 0x7FFFu + ((x.i >> 16) & 1u);
  return (unsigned short)(r >> 16);
}
// fp8 e5m2 (OCP) = top byte of f16. Encode: f32->f16 then RNE-round top byte.
__device__ __forceinline__ unsigned char f2bf8(float f) {
  union { __half h; unsigned short u; } x;
  x.h = __float2half(fminf(f, 57344.0f));  // clamp below e5m2 max, no inf
  unsigned short r = (unsigned short)(x.u + 0x7F + ((x.u >> 8) & 1));
  return (unsigned char)(r >> 8);
}
__device__ __forceinline__ float bf8tof(unsigned char b) {
  union { unsigned short u; __half h; } x; x.u = (unsigned short)((unsigned int)b << 8);
  return __half2float(x.h);
}
__device__ __forceinline__ void decode8(uint2 kv, float* k) {
#if __has_builtin(__builtin_amdgcn_cvt_pk_f32_bf8)
  f32x2 p;
  p = __builtin_amdgcn_cvt_pk_f32_bf8((int)kv.x, false); k[0] = p[0]; k[1] = p[1];
  p = __builtin_amdgcn_cvt_pk_f32_bf8((int)kv.x, true);  k[2] = p[0]; k[3] = p[1];
  p = __builtin_amdgcn_cvt_pk_f32_bf8((int)kv.y, false); k[4] = p[0]; k[5] = p[1];
  p = __builtin_amdgcn_cvt_pk_f32_bf8((int)kv.y, true);  k[6] = p[0]; k[7] = p[1];
#else
  #pragma unroll
  for (int i = 0; i < 4; ++i) k[i] = bf8tof((unsigned char)((kv.x >> (8 * i)) & 0xFF));
  #pragma unroll
  for (int i = 0; i < 4; ++i) k[4 + i] = bf8tof((unsigned char)((kv.y >> (8 * i)) & 0xFF));
#endif
}

#define GLD_LDS16(g, l)                                                          \
  __builtin_amdgcn_global_load_lds(                                              \
      (const __attribute__((address_space(1))) unsigned int*)(g),                \
      (__attribute__((address_space(3))) unsigned int*)(l), 16, 0, 0)

// ---------------- 1. fp32 -> bf16 cast ----------------
__global__ __launch_bounds__(256) void cast_bf16_kernel(const float* __restrict__ src,
                                                        unsigned short* __restrict__ dst,
                                                        int n4) {
  int i = blockIdx.x * blockDim.x + threadIdx.x;
  if (i < n4) {
    float4 f = reinterpret_cast<const float4*>(src)[i];
    ushort4 o;
    o.x = f2bf(f.x); o.y = f2bf(f.y); o.z = f2bf(f.z); o.w = f2bf(f.w);
    reinterpret_cast<ushort4*>(dst)[i] = o;
  }
}

// ---------------- 2. diagonal dot -> column scale exponent ----------------
// E_j = round((1 - S_jj)*100*log2 e); column j of K is scaled by 2^E_j.
__global__ __launch_bounds__(256) void diag_scale_kernel(const unsigned short* __restrict__ Abf,
                                                         const unsigned short* __restrict__ Bbf,
                                                         float* __restrict__ Ecol) {
  const int t = threadIdx.x, lane = t & 63, wid = t >> 6;
  const int rowg = lane >> 4, seg = lane & 15;
  const int row = blockIdx.x * 16 + wid * 4 + rowg;
  const unsigned short* a = Abf + (size_t)row * D_DIM + seg * 16;
  const unsigned short* b = Bbf + (size_t)row * D_DIM + seg * 16;
  float s = 0.0f;
  #pragma unroll
  for (int h = 0; h < 2; ++h) {
    short8 av = *reinterpret_cast<const short8*>(a + h * 8);
    short8 bv = *reinterpret_cast<const short8*>(b + h * 8);
    #pragma unroll
    for (int e = 0; e < 8; ++e)
      s += bf2f((unsigned short)av[e]) * bf2f((unsigned short)bv[e]);
  }
  s += __shfl_xor(s, 1, 64); s += __shfl_xor(s, 2, 64);
  s += __shfl_xor(s, 4, 64); s += __shfl_xor(s, 8, 64);
  if (seg == 0) Ecol[row] = rintf((1.0f - s) * L2E100);
}

// ---------------- 3. GEMM + exp2 + column-scale + fp8 store ----------------
// 128x128 tile, BK=32 (8 steps), 4 waves (2x2), wave tile 64x64 (4x4 frags).
// Double-buffered LDS staged via global_load_lds(16B); XOR-swizzled layout
// (pre-swizzled global source + swizzled ds_read -> <=2-way bank conflicts).
__global__ __launch_bounds__(256) void gemm_exp_fp8_kernel(const unsigned short* __restrict__ A,
                                                           const unsigned short* __restrict__ B,
                                                           const float* __restrict__ Ecol,
                                                           unsigned char* __restrict__ Kout) {
  __shared__ __align__(16) char smem[32768];  // 2 bufs x (A 8K + B 8K); epilogue aliases
  const int bi = blockIdx.y, bj = blockIdx.x;
  const int t = threadIdx.x, lane = t & 63, wid = t >> 6;
  const int wr = wid >> 1, wc = wid & 1;
  const int al = lane & 15, kh = lane >> 4;

  // staging coords: thread t owns LDS slot (row = t>>2 [+64], 16B-chunk cb = t&3);
  // it fetches global chunk g = cb ^ swz(row), swz(r) = (r + (r>>2)) & 3.
  const int sr = t >> 2, scb = t & 3;
  const int r0 = sr, r1 = sr + 64;
  const int g0 = scb ^ ((r0 + (r0 >> 2)) & 3);
  const int g1 = scb ^ ((r1 + (r1 >> 2)) & 3);
  const unsigned short* A0 = A + (size_t)(bi * 128 + r0) * D_DIM + g0 * 8;
  const unsigned short* A1 = A + (size_t)(bi * 128 + r1) * D_DIM + g1 * 8;
  const unsigned short* B0 = B + (size_t)(bj * 128 + r0) * D_DIM + g0 * 8;
  const unsigned short* B1 = B + (size_t)(bj * 128 + r1) * D_DIM + g1 * 8;

  float e4[4];
  #pragma unroll
  for (int n = 0; n < 4; ++n) e4[n] = Ecol[bj * 128 + wc * 64 + n * 16 + al];

  // fragment LDS byte offsets (within one buffer), swizzled to match staging
  int offA[4], offB[4];
  #pragma unroll
  for (int m = 0; m < 4; ++m) {
    int ra = wr * 64 + m * 16 + al;
    offA[m] = ra * 64 + ((kh ^ ((ra + (ra >> 2)) & 3)) << 4);
    int rb = wc * 64 + m * 16 + al;
    offB[m] = rb * 64 + ((kh ^ ((rb + (rb >> 2)) & 3)) << 4);
  }

  f32x4 acc[4][4] = {};

  #define STAGE(kk, buf)                                        \
    do {                                                        \
      char* sb = smem + (buf) * 16384;                          \
      GLD_LDS16(A0 + (kk) * 32, sb + t * 16);                   \
      GLD_LDS16(A1 + (kk) * 32, sb + 4096 + t * 16);            \
      GLD_LDS16(B0 + (kk) * 32, sb + 8192 + t * 16);            \
      GLD_LDS16(B1 + (kk) * 32, sb + 12288 + t * 16);           \
    } while (0)

  STAGE(0, 0);
  __syncthreads();
  #pragma unroll
  for (int kk = 0; kk < 8; ++kk) {
    const int buf = kk & 1;
    if (kk < 7) STAGE(kk + 1, buf ^ 1);
    const char* sb = smem + buf * 16384;
    short8 a[4], b[4];
    #pragma unroll
    for (int m = 0; m < 4; ++m) a[m] = *reinterpret_cast<const short8*>(sb + offA[m]);
    #pragma unroll
    for (int n = 0; n < 4; ++n) b[n] = *reinterpret_cast<const short8*>(sb + 8192 + offB[n]);
    #pragma unroll
    for (int m = 0; m < 4; ++m)
      #pragma unroll
      for (int n = 0; n < 4; ++n)
        acc[m][n] = __builtin_amdgcn_mfma_f32_16x16x32_bf16(a[m], b[n], acc[m][n], 0, 0, 0);
    __syncthreads();
  }
  #undef STAGE

  // epilogue: K'_ij = exp2((S-1)*100*log2e + E_j) -> fp8, via LDS repack (stride 144B)
  unsigned char* Cs = (unsigned char*)smem;  // 128 x 144
  #pragma unroll
  for (int m = 0; m < 4; ++m)
    #pragma unroll
    for (int n = 0; n < 4; ++n)
      #pragma unroll
      for (int q = 0; q < 4; ++q) {
        float s = acc[m][n][q];
        float kv = exp2f((s - 1.0f) * L2E100 + e4[n]);
        int rr = wr * 64 + m * 16 + kh * 4 + q;  // C/D: col=lane&15, row=(lane>>4)*4+q
        int cc = wc * 64 + n * 16 + al;
        Cs[rr * 144 + cc] = f2bf8(kv);
      }
  __syncthreads();
  const int row = t >> 1, half = (t & 1) * 64;
  size_t gb = (size_t)(bi * 128 + row) * N_DIM + bj * 128 + half;
  #pragma unroll
  for (int c = 0; c < 4; ++c)
    *reinterpret_cast<uint4*>(Kout + gb + c * 16) =
        *reinterpret_cast<const uint4*>(Cs + row * 144 + half + c * 16);
}

// ---------------- 4. init ----------------
__global__ __launch_bounds__(256) void init_vecs_kernel(float* __restrict__ u,
                                                        float* __restrict__ u2,
                                                        float* __restrict__ out) {
  int i = blockIdx.x * blockDim.x + threadIdx.x;
  if (i < N_DIM) { u[i] = 1.0f / N_DIM; u2[i] = 1.0f / N_DIM; }
  if (i == 0) out[0] = 0.0f;
}

// ---------------- 5. dual matvec (fp8) ----------------
// rowsum_i = sum_j K_ij*wcol_j ; colpart[b][j] = sum_{i in stripe} K_ij*wrow_i
// 256 blocks x 1024 thr, 32 rows x 8192 cols per block. Row reduce batched via LDS.
__global__ __launch_bounds__(1024) void dual_matvec_fp8_kernel(const unsigned char* __restrict__ K8,
                                                               const float* __restrict__ wrow,
                                                               const float* __restrict__ wcol,
                                                               float* __restrict__ rowsum,
                                                               float* __restrict__ colpart) {
  const int b = blockIdx.x;
  const int t = threadIdx.x;
  const int c0 = t * 8;
  const int row0 = b * 32;

  float wc8[8];
  {
    float4 w0 = *reinterpret_cast<const float4*>(wcol + c0);
    float4 w1 = *reinterpret_cast<const float4*>(wcol + c0 + 4);
    wc8[0] = w0.x; wc8[1] = w0.y; wc8[2] = w0.z; wc8[3] = w0.w;
    wc8[4] = w1.x; wc8[5] = w1.y; wc8[6] = w1.z; wc8[7] = w1.w;
  }
  float colacc[8] = {0, 0, 0, 0, 0, 0, 0, 0};
  __shared__ float pbuf[8][1024];

  for (int batch = 0; batch < 4; ++batch) {
    #pragma unroll
    for (int rr = 0; rr < 8; ++rr) {
      const int r = batch * 8 + rr;
      float wr = wrow[row0 + r];
      uint2 kv = *reinterpret_cast<const uint2*>(K8 + (size_t)(row0 + r) * N_DIM + c0);
      float k[8];
      decode8(kv, k);
      float p = 0.0f;
      #pragma unroll
      for (int e = 0; e < 8; ++e) {
        p += k[e] * wc8[e];
        colacc[e] += k[e] * wr;
      }
      pbuf[rr][t] = p;
    }
    __syncthreads();
    if (t < 512) {  // waves 0..7: wave w reduces row batch*8+w
      const int w = t >> 6, l = t & 63;
      float s = 0.0f;
      #pragma unroll
      for (int i = 0; i < 16; ++i) s += pbuf[w][l + i * 64];
      #pragma unroll
      for (int off = 32; off > 0; off >>= 1) s += __shfl_down(s, off, 64);
      if (l == 0) rowsum[row0 + batch * 8 + w] = s;
    }
    __syncthreads();
  }
  *reinterpret_cast<float4*>(colpart + (size_t)b * N_DIM + c0) =
      make_float4(colacc[0], colacc[1], colacc[2], colacc[3]);
  *reinterpret_cast<float4*>(colpart + (size_t)b * N_DIM + c0 + 4) =
      make_float4(colacc[4], colacc[5], colacc[6], colacc[7]);
}

// ---------------- 6. reduce col partials + transform ----------------
__global__ __launch_bounds__(256) void reduce_transform_kernel(const float* __restrict__ colpart,
                                                               const float* __restrict__ rowsum,
                                                               float* __restrict__ colvec_out,
                                                               float* __restrict__ rowvec_out,
                                                               float coeff) {
  int b = blockIdx.x;
  int jloc = threadIdx.x & 31;
  int chunk = threadIdx.x >> 5;
  int j = b * 32 + jloc;
  float s = 0.0f;
  for (int st = chunk * 32; st < chunk * 32 + 32; ++st)
    s += colpart[(size_t)st * N_DIM + j];
  __shared__ float red[8][32];
  red[chunk][jloc] = s;
  __syncthreads();
  if (threadIdx.x < 32) {
    int jj = b * 32 + threadIdx.x;
    float tot = 0.0f;
    #pragma unroll
    for (int c = 0; c < 8; ++c) tot += red[c][threadIdx.x];
    colvec_out[jj] = coeff / tot;
    rowvec_out[jj] = coeff / rowsum[jj];
  }
}

// ---------------- 7. final pass: softmax denominators ----------------
__global__ __launch_bounds__(1024) void final_dual_fp8_kernel(const unsigned char* __restrict__ K8,
                                                              const float* __restrict__ u,
                                                              const float* __restrict__ v,
                                                              const float* __restrict__ u2,
                                                              const float* __restrict__ v2,
                                                              float* __restrict__ rowsumE,
                                                              float* __restrict__ colpartE) {
  const int b = blockIdx.x;
  const int t = threadIdx.x;
  const int c0 = t * 8;
  const int row0 = b * 32;

  float v8[8], u28[8];
  {
    float4 a0 = *reinterpret_cast<const float4*>(v + c0);
    float4 a1 = *reinterpret_cast<const float4*>(v + c0 + 4);
    v8[0] = a0.x; v8[1] = a0.y; v8[2] = a0.z; v8[3] = a0.w;
    v8[4] = a1.x; v8[5] = a1.y; v8[6] = a1.z; v8[7] = a1.w;
    float4 b0 = *reinterpret_cast<const float4*>(u2 + c0);
    float4 b1 = *reinterpret_cast<const float4*>(u2 + c0 + 4);
    u28[0] = b0.x; u28[1] = b0.y; u28[2] = b0.z; u28[3] = b0.w;
    u28[4] = b1.x; u28[5] = b1.y; u28[6] = b1.z; u28[7] = b1.w;
  }
  float colacc[8] = {0, 0, 0, 0, 0, 0, 0, 0};
  __shared__ float pbuf[8][1024];

  for (int batch = 0; batch < 4; ++batch) {
    #pragma unroll
    for (int rr = 0; rr < 8; ++rr) {
      const int r = batch * 8 + rr;
      float ui = u[row0 + r];
      float v2i = v2[row0 + r];
      uint2 kv = *reinterpret_cast<const uint2*>(K8 + (size_t)(row0 + r) * N_DIM + c0);
      float k[8];
      decode8(kv, k);
      float p = 0.0f;
      #pragma unroll
      for (int e = 0; e < 8; ++e) {
        p += __expf(ui * k[e] * v8[e]);
        colacc[e] += __expf(u28[e] * k[e] * v2i);
      }
      pbuf[rr][t] = p;
    }
    __syncthreads();
    if (t < 512) {
      const int w = t >> 6, l = t & 63;
      float s = 0.0f;
      #pragma unroll
      for (int i = 0; i < 16; ++i) s += pbuf[w][l + i * 64];
      #pragma unroll
      for (int off = 32; off > 0; off >>= 1) s += __shfl_down(s, off, 64);
      if (l == 0) rowsumE[row0 + batch * 8 + w] = s;
    }
    __syncthreads();
  }
  *reinterpret_cast<float4*>(colpartE + (size_t)b * N_DIM + c0) =
      make_float4(colacc[0], colacc[1], colacc[2], colacc[3]);
  *reinterpret_cast<float4*>(colpartE + (size_t)b * N_DIM + c0 + 4) =
      make_float4(colacc[4], colacc[5], colacc[6], colacc[7]);
}

// ---------------- 8. final reduction -> scalar loss ----------------
__global__ __launch_bounds__(256) void final_reduce_kernel(const float* __restrict__ colpartE,
                                                           const float* __restrict__ rowsumE,
                                                           const unsigned char* __restrict__ K8,
                                                           const float* __restrict__ u,
                                                           const float* __restrict__ v,
                                                           const float* __restrict__ u2,
                                                           const float* __restrict__ v2,
                                                           float* __restrict__ out) {
  int b = blockIdx.x;
  int jloc = threadIdx.x & 31;
  int chunk = threadIdx.x >> 5;
  int j = b * 32 + jloc;
  float s = 0.0f;
  for (int st = chunk * 32; st < chunk * 32 + 32; ++st)
    s += colpartE[(size_t)st * N_DIM + j];
  __shared__ float red[8][32];
  red[chunk][jloc] = s;
  __syncthreads();
  if (threadIdx.x < 32) {
    int i = b * 32 + threadIdx.x;
    float s2 = 0.0f;
    #pragma unroll
    for (int c = 0; c < 8; ++c) s2 += red[c][threadIdx.x];
    float kd = bf8tof(K8[(size_t)i * N_DIM + i]);
    float l1 = logf(rowsumE[i]) - u[i] * kd * v[i];
    float l2 = logf(s2) - u2[i] * kd * v2[i];
    float val = l1 + l2;
    #pragma unroll
    for (int o = 16; o > 0; o >>= 1) val += __shfl_down(val, o, 64);
    if (threadIdx.x == 0) atomicAdd(out, val * (0.5f / (float)N_DIM));
  }
}

// ---------------- launch ----------------
extern "C" void kernel_launch(void* const* d_in, const int* in_sizes, int n_in,
                              void* d_out, int out_size, void* d_ws, size_t ws_size,
                              hipStream_t stream) {
  const float* img = (const float*)d_in[0];
  const float* txt = (const float*)d_in[1];
  float* out = (float*)d_out;

  char* ws = (char*)d_ws;
  size_t off = 0;
  auto alloc = [&](size_t bytes) -> void* {
    void* p = ws + off;
    off += (bytes + 255) & ~(size_t)255;
    return p;
  };
  unsigned char* Km   = (unsigned char*)alloc((size_t)N_DIM * N_DIM);  // 64 MiB fp8
  unsigned short* Abf = (unsigned short*)alloc((size_t)N_DIM * D_DIM * 2);
  unsigned short* Bbf = (unsigned short*)alloc((size_t)N_DIM * D_DIM * 2);
  float* Ecol    = (float*)alloc(N_DIM * 4);
  float* u       = (float*)alloc(N_DIM * 4);
  float* u2      = (float*)alloc(N_DIM * 4);
  float* v       = (float*)alloc(N_DIM * 4);
  float* v2      = (float*)alloc(N_DIM * 4);
  float* rowsum  = (float*)alloc(N_DIM * 4);
  float* colpart = (float*)alloc((size_t)256 * N_DIM * 4);  // 8 MiB

  if (off > ws_size) {
    hipMemsetAsync(d_out, 0xFF, sizeof(float) * (out_size > 0 ? out_size : 1), stream);
    return;
  }

  const int n4 = N_DIM * D_DIM / 4;
  cast_bf16_kernel<<<(n4 + 255) / 256, 256, 0, stream>>>(img, Abf, n4);
  cast_bf16_kernel<<<(n4 + 255) / 256, 256, 0, stream>>>(txt, Bbf, n4);
  diag_scale_kernel<<<512, 256, 0, stream>>>(Abf, Bbf, Ecol);
  gemm_exp_fp8_kernel<<<dim3(64, 64), 256, 0, stream>>>(Abf, Bbf, Ecol, Km);
  init_vecs_kernel<<<32, 256, 0, stream>>>(u, u2, out);

  const float bval = 1.0f / (float)N_DIM;
  for (int it = 0; it < 5; ++it) {
    dual_matvec_fp8_kernel<<<256, 1024, 0, stream>>>(Km, u, u2, rowsum, colpart);
    reduce_transform_kernel<<<256, 256, 0, stream>>>(colpart, rowsum, v, v2, bval);
    dual_matvec_fp8_kernel<<<256, 1024, 0, stream>>>(Km, v2, v, rowsum, colpart);
    reduce_transform_kernel<<<256, 256, 0, stream>>>(colpart, rowsum, u2, u, 1.0f);
  }

  final_dual_fp8_kernel<<<256, 1024, 0, stream>>>(Km, u, v, u2, v2, rowsum, colpart);
  final_reduce_kernel<<<256, 256, 0, stream>>>(colpart, rowsum, Km, u, v, u2, v2, out);
}